// Round 9
// baseline (430.206 us; speedup 1.0000x reference)
//
#include <hip/hip_runtime.h>
#include <hip/hip_fp16.h>

#define HASH_PRIME 5099
#define NE 64
#define ND 512
#define NF 1792
#define NS 32768
#define CAP 512

typedef unsigned short u16;
typedef __attribute__((ext_vector_type(8))) short bf16x8;
typedef __attribute__((ext_vector_type(4))) float f32x4;

__device__ __forceinline__ u16 f2bf(float f) {
  union { float f; unsigned u; } v; v.f = f;
  return (u16)((v.u + 0x7FFFu + ((v.u >> 16) & 1u)) >> 16);
}
__device__ __forceinline__ unsigned pkbf2(float a, float b) {
  return (unsigned)f2bf(a) | ((unsigned)f2bf(b) << 16);
}
__device__ __forceinline__ unsigned pkh2(float a, float b) {
  __half2 h = __floats2half2_rn(a, b);
  return __builtin_bit_cast(unsigned, h);
}
__device__ __forceinline__ float uph(unsigned w, int hi) {
  __half2 h = __builtin_bit_cast(__half2, w);
  return hi ? __high2float(h) : __low2float(h);
}

// async global->LDS, 16B per lane. LDS dest is wave-uniform base + lane*16.
__device__ __forceinline__ void gld16(const void* g, void* l) {
  __builtin_amdgcn_global_load_lds(
      (const __attribute__((address_space(1))) unsigned int*)(uintptr_t)g,
      (__attribute__((address_space(3))) unsigned int*)(uintptr_t)l,
      16, 0, 0);
}

// ---------------- routing ----------------
__global__ __launch_bounds__(512) void route1(const int* __restrict__ tok,
                                              int* __restrict__ rank_local,
                                              int* __restrict__ hist) {
  __shared__ int se[512];
  __shared__ int h[NE];
  int b = blockIdx.x, t = threadIdx.x;
  int s = b * 512 + t;
  int e = (tok[s] % HASH_PRIME) % NE;
  se[t] = e;
  if (t < NE) h[t] = 0;
  __syncthreads();
  int cnt = 0;
  for (int j = 0; j < t; ++j) cnt += (se[j] == e);
  rank_local[s] = cnt;
  atomicAdd(&h[e], 1);
  __syncthreads();
  if (t < NE) hist[b * NE + t] = h[t];
}

__global__ __launch_bounds__(512) void route2(const int* __restrict__ tok,
                                              const int* __restrict__ rank_local,
                                              const int* __restrict__ hist,
                                              int* __restrict__ slot_src) {
  __shared__ int off[NE];
  int b = blockIdx.x, t = threadIdx.x;
  if (t < NE) {
    int o = 0;
    for (int bb = 0; bb < b; ++bb) o += hist[bb * NE + t];
    off[t] = o;
  }
  __syncthreads();
  int s = b * 512 + t;
  int e = (tok[s] % HASH_PRIME) % NE;
  int pos = off[e] + rank_local[s];
  if (pos < CAP) slot_src[e * CAP + pos] = s;
}

// ---------------- dispatch: gather X -> bf16 Xd[E,CAP,D] ----------------
__global__ __launch_bounds__(256) void dispatchx(const float* __restrict__ x,
                                                 const int* __restrict__ slot_src,
                                                 u16* __restrict__ Xd) {
  int b = blockIdx.x;
  int t = threadIdx.x;
  int row = b * 4 + (t >> 6);
  int col = (t & 63) * 8;
  int s = slot_src[row];
  uint4 w = make_uint4(0u, 0u, 0u, 0u);
  if (s >= 0) {
    const float4* p = (const float4*)(x + (size_t)s * ND + col);
    float4 a = p[0], c = p[1];
    w.x = pkbf2(a.x, a.y); w.y = pkbf2(a.z, a.w);
    w.z = pkbf2(c.x, c.y); w.w = pkbf2(c.z, c.w);
  }
  *(uint4*)(Xd + (size_t)row * ND + col) = w;
}

// ---------------- GEMM machinery (m97-class, VERIFIED round-3/5) ----------------
// 128x128 tile, BK=32, 256 threads = 4 waves (2m x 2n), each wave 64x64 via
// 4x4 mfma_f32_16x16x32_bf16. LDS 32KB total -> 4+ blocks/CU for drain overlap.
// Swizzle (verified 0 conflicts in r5): halfword idx = r*32 + ((kb^((r>>1)&3))*8) + j.
// A staged via global_load_lds with pre-swizzled per-lane global source
// (same involution both sides, linear LDS dest — rule 21).

#define GDECL \
  __shared__ u16 As[2][128 * 32]; \
  __shared__ u16 Bs[2][128 * 32]; \
  const int t = threadIdx.x; \
  const int l = t & 63; \
  const int w = t >> 6; \
  const int wm = w >> 1; \
  const int wn = w & 1; \
  const int lrow = l & 15; \
  const int swz = ((l >> 4) ^ ((l >> 1) & 3)) * 8; \
  const int ra_row = t >> 2; \
  const int ra_col = ((t & 3) ^ ((t >> 3) & 3)) * 8; \
  const int brow_ = t >> 1; \
  const int bseg = t & 1; \
  const int wb0 = brow_ * 32 + (((bseg * 2)     ^ ((t >> 2) & 3)) * 8); \
  const int wb1 = brow_ * 32 + (((bseg * 2 + 1) ^ ((t >> 2) & 3)) * 8);

#define INIT_ACC do { \
  _Pragma("unroll") for (int m_ = 0; m_ < 4; ++m_) \
    _Pragma("unroll") for (int n_ = 0; n_ < 4; ++n_) \
      acc[m_][n_] = (f32x4){0.f, 0.f, 0.f, 0.f}; \
} while (0)

#define ISSUE_A(buf, ks, abase, astride) do { \
  const u16* g_ = (abase) + (size_t)ra_row * (astride) + (ks) * 32 + ra_col; \
  gld16(g_, (char*)As[buf] + t * 16); \
  gld16(g_ + (size_t)64 * (astride), (char*)As[buf] + t * 16 + 4096); \
} while (0)

#define LOAD_B(ks, bbase, bstride) do { \
  const float4* p_ = (const float4*)((bbase) + (size_t)brow_ * (bstride) + (ks) * 32 + bseg * 16); \
  fb0 = p_[0]; fb1 = p_[1]; fb2 = p_[2]; fb3 = p_[3]; \
} while (0)

#define WRITE_B(buf) do { \
  uint4 w0_, w1_; \
  w0_.x = pkbf2(fb0.x, fb0.y); w0_.y = pkbf2(fb0.z, fb0.w); \
  w0_.z = pkbf2(fb1.x, fb1.y); w0_.w = pkbf2(fb1.z, fb1.w); \
  w1_.x = pkbf2(fb2.x, fb2.y); w1_.y = pkbf2(fb2.z, fb2.w); \
  w1_.z = pkbf2(fb3.x, fb3.y); w1_.w = pkbf2(fb3.z, fb3.w); \
  *(uint4*)&Bs[buf][wb0] = w0_; \
  *(uint4*)&Bs[buf][wb1] = w1_; \
} while (0)

#define COMPUTE(buf) do { \
  bf16x8 af_[4], bf_[4]; \
  _Pragma("unroll") for (int m_ = 0; m_ < 4; ++m_) \
    af_[m_] = *(const bf16x8*)&As[buf][(wm * 64 + m_ * 16 + lrow) * 32 + swz]; \
  _Pragma("unroll") for (int n_ = 0; n_ < 4; ++n_) \
    bf_[n_] = *(const bf16x8*)&Bs[buf][(wn * 64 + n_ * 16 + lrow) * 32 + swz]; \
  _Pragma("unroll") for (int m_ = 0; m_ < 4; ++m_) \
    _Pragma("unroll") for (int n_ = 0; n_ < 4; ++n_) \
      acc[m_][n_] = __builtin_amdgcn_mfma_f32_16x16x32_bf16(af_[m_], bf_[n_], acc[m_][n_], 0, 0, 0); \
} while (0)

#define GEMM_LOOP(NK, abase, astride, bbase, bstride) do { \
  float4 fb0, fb1, fb2, fb3; \
  ISSUE_A(0, 0, abase, astride); \
  LOAD_B(0, bbase, bstride); \
  WRITE_B(0); \
  __syncthreads(); \
  _Pragma("unroll 2") \
  for (int ks = 0; ks < (NK); ++ks) { \
    const int cur = ks & 1; \
    if (ks + 1 < (NK)) { \
      ISSUE_A(cur ^ 1, ks + 1, abase, astride); \
      LOAD_B(ks + 1, bbase, bstride); \
    } \
    COMPUTE(cur); \
    if (ks + 1 < (NK)) WRITE_B(cur ^ 1); \
    __syncthreads(); \
  } \
} while (0)

// ---------------- G1: H = relu(Xd Wk^T)^2, bf16 ----------------
__global__ __launch_bounds__(256, 4) void g1(const u16* __restrict__ Xd,
                                             const float* __restrict__ Wk,
                                             u16* __restrict__ H) {
  GDECL
  // 3584 blocks: bijective XCD swizzle, 8 experts/XCD, m innermost
  const int wg = (blockIdx.x & 7) * 448 + (blockIdx.x >> 3);
  const int e = wg / 56, rem = wg % 56;
  const int m0 = (rem & 3) * 128;
  const int n0 = (rem >> 2) * 128;
  f32x4 acc[4][4];
  INIT_ACC;
  const u16*   abase = Xd + ((size_t)e * CAP + m0) * ND;
  const float* bbase = Wk + ((size_t)e * NF + n0) * ND;
  GEMM_LOOP(16, abase, ND, bbase, ND);

  #pragma unroll
  for (int m = 0; m < 4; ++m) {
    #pragma unroll
    for (int i = 0; i < 4; ++i) {
      int r = m0 + wm * 64 + m * 16 + (l >> 4) * 4 + i;
      size_t base = ((size_t)e * CAP + r) * NF + n0 + wn * 64 + lrow;
      #pragma unroll
      for (int n = 0; n < 4; ++n) {
        float v = acc[m][n][i];
        v = v > 0.f ? v * v : 0.f;
        H[base + n * 16] = f2bf(v);
      }
    }
  }
}

// ---------------- G2 (fused): out = sigmoid(Xd Wr^T) * (H Wv^T), scatter ----------------
__global__ __launch_bounds__(256, 4) void g2(const u16* __restrict__ Xd,
                                             const float* __restrict__ Wr,
                                             const u16* __restrict__ H,
                                             const float* __restrict__ Wv,
                                             const int* __restrict__ slot_src,
                                             float* __restrict__ out) {
  GDECL
  __shared__ int ss[128];
  // 1024 blocks: bijective XCD swizzle, 8 experts/XCD, m innermost
  const int wg = (blockIdx.x & 7) * 128 + (blockIdx.x >> 3);
  const int e = wg >> 4, rem = wg & 15;
  const int m0 = (rem & 3) * 128;
  const int n0 = (rem >> 2) * 128;
  if (t < 128) ss[t] = slot_src[e * CAP + m0 + t];
  f32x4 acc[4][4];

  // ---- phase 1: zr = Xd Wr^T ----
  INIT_ACC;
  {
    const u16*   abase = Xd + ((size_t)e * CAP + m0) * ND;
    const float* bbase = Wr + ((size_t)e * ND + n0) * ND;
    GEMM_LOOP(16, abase, ND, bbase, ND);
  }

  // pack r = sigmoid(zr) as fp16 pairs (rel err ~5e-4)
  unsigned rpk[4][4][2];
  #pragma unroll
  for (int m = 0; m < 4; ++m) {
    #pragma unroll
    for (int n = 0; n < 4; ++n) {
      float r0 = 1.f / (1.f + __expf(-acc[m][n][0]));
      float r1 = 1.f / (1.f + __expf(-acc[m][n][1]));
      float r2 = 1.f / (1.f + __expf(-acc[m][n][2]));
      float r3 = 1.f / (1.f + __expf(-acc[m][n][3]));
      rpk[m][n][0] = pkh2(r0, r1);
      rpk[m][n][1] = pkh2(r2, r3);
    }
  }

  // ---- phase 2: kv = H Wv^T ----
  INIT_ACC;
  {
    const u16*   abase = H  + ((size_t)e * CAP + m0) * NF;
    const float* bbase = Wv + ((size_t)e * ND + n0) * NF;
    GEMM_LOOP(56, abase, NF, bbase, NF);
  }

  // epilogue: out = r * kv, scatter (dropped tokens stay 0)
  #pragma unroll
  for (int m = 0; m < 4; ++m) {
    #pragma unroll
    for (int i = 0; i < 4; ++i) {
      int rl = wm * 64 + m * 16 + (l >> 4) * 4 + i;  // tile-local row
      int s = ss[rl];
      if (s >= 0) {
        float* op = out + (size_t)s * ND + n0 + wn * 64 + lrow;
        #pragma unroll
        for (int n = 0; n < 4; ++n) {
          op[n * 16] = uph(rpk[m][n][i >> 1], i & 1) * acc[m][n][i];
        }
      }
    }
  }
}

extern "C" void kernel_launch(void* const* d_in, const int* in_sizes, int n_in,
                              void* d_out, int out_size, void* d_ws, size_t ws_size,
                              hipStream_t stream) {
  const float* x   = (const float*)d_in[0];
  const int*   tok = (const int*)d_in[1];
  const float* Wk  = (const float*)d_in[2];
  const float* Wr  = (const float*)d_in[3];
  const float* Wv  = (const float*)d_in[4];
  float* out = (float*)d_out;

  char* ws = (char*)d_ws;
  int*    slot_src   = (int*)ws;                 // 131072 B
  int*    rank_local = (int*)(ws + 131072);      // 131072 B
  int*    hist       = (int*)(ws + 262144);      // 16384 B
  u16*    Xd         = (u16*)(ws + (1 << 20));   // 33.5 MB
  u16*    Hbuf       = (u16*)(ws + 68157440);    // 117.4 MB

  (void)hipMemsetAsync(d_out, 0, (size_t)out_size * sizeof(float), stream);
  (void)hipMemsetAsync(slot_src, 0xFF, NE * CAP * sizeof(int), stream);
  route1<<<64, 512, 0, stream>>>(tok, rank_local, hist);
  route2<<<64, 512, 0, stream>>>(tok, rank_local, hist, slot_src);
  dispatchx<<<NS / 4, 256, 0, stream>>>(x, slot_src, Xd);
  g1<<<3584, 256, 0, stream>>>(Xd, Wk, Hbuf);
  g2<<<1024, 256, 0, stream>>>(Xd, Wr, Hbuf, Wv, slot_src, out);
}

// Round 10
// 383.115 us; speedup vs baseline: 1.1229x; 1.1229x over previous
//
#include <hip/hip_runtime.h>
#include <hip/hip_fp16.h>

#define HASH_PRIME 5099
#define NE 64
#define ND 512
#define NF 1792
#define NS 32768
#define CAP 512

typedef unsigned short u16;
typedef __attribute__((ext_vector_type(8))) short bf16x8;
typedef __attribute__((ext_vector_type(4))) float f32x4;

__device__ __forceinline__ u16 f2bf(float f) {
  union { float f; unsigned u; } v; v.f = f;
  return (u16)((v.u + 0x7FFFu + ((v.u >> 16) & 1u)) >> 16);
}
__device__ __forceinline__ unsigned pkbf2(float a, float b) {
  return (unsigned)f2bf(a) | ((unsigned)f2bf(b) << 16);
}

__device__ __forceinline__ void gld16(const void* g, void* l) {
  __builtin_amdgcn_global_load_lds(
      (const __attribute__((address_space(1))) unsigned int*)(uintptr_t)g,
      (__attribute__((address_space(3))) unsigned int*)(uintptr_t)l,
      16, 0, 0);
}

// ---------------- routing ----------------
__global__ __launch_bounds__(512) void route1(const int* __restrict__ tok,
                                              int* __restrict__ rank_local,
                                              int* __restrict__ hist) {
  __shared__ int se[512];
  __shared__ int h[NE];
  int b = blockIdx.x, t = threadIdx.x;
  int s = b * 512 + t;
  int e = (tok[s] % HASH_PRIME) % NE;
  se[t] = e;
  if (t < NE) h[t] = 0;
  __syncthreads();
  int cnt = 0;
  for (int j = 0; j < t; ++j) cnt += (se[j] == e);
  rank_local[s] = cnt;
  atomicAdd(&h[e], 1);
  __syncthreads();
  if (t < NE) hist[b * NE + t] = h[t];
}

__global__ __launch_bounds__(512) void route2(const int* __restrict__ tok,
                                              const int* __restrict__ rank_local,
                                              const int* __restrict__ hist,
                                              int* __restrict__ slot_src) {
  __shared__ int off[NE];
  int b = blockIdx.x, t = threadIdx.x;
  if (t < NE) {
    int o = 0;
    for (int bb = 0; bb < b; ++bb) o += hist[bb * NE + t];
    off[t] = o;
  }
  __syncthreads();
  int s = b * 512 + t;
  int e = (tok[s] % HASH_PRIME) % NE;
  int pos = off[e] + rank_local[s];
  if (pos < CAP) slot_src[e * CAP + pos] = s;
}

// ---------------- dispatch: gather X -> bf16 Xd[E,CAP,D] ----------------
__global__ __launch_bounds__(256) void dispatchx(const float* __restrict__ x,
                                                 const int* __restrict__ slot_src,
                                                 u16* __restrict__ Xd) {
  int b = blockIdx.x;
  int t = threadIdx.x;
  int row = b * 4 + (t >> 6);
  int col = (t & 63) * 8;
  int s = slot_src[row];
  uint4 w = make_uint4(0u, 0u, 0u, 0u);
  if (s >= 0) {
    const float4* p = (const float4*)(x + (size_t)s * ND + col);
    float4 a = p[0], c = p[1];
    w.x = pkbf2(a.x, a.y); w.y = pkbf2(a.z, a.w);
    w.z = pkbf2(c.x, c.y); w.w = pkbf2(c.z, c.w);
  }
  *(uint4*)(Xd + (size_t)row * ND + col) = w;
}

// ---------------- 4-phase pipelined GEMM core ----------------
// 256x256 tile, BK=64 K-tiles, 8 waves (2m x 4n), 512 threads.
// LDS: A,B each [2 slots][256 rows][64 k] bf16; ONE SLOT = 256*64*2B = 32768 B
// = 16384 halfwords (r10 fix: r6-r8 used 2x slot stride -> OOB writes into the
// other operand's buffer / off the end => deterministic garbage on odd tiles).
// Swizzle: halfword idx = row*64 + ((k>>3) ^ (row&7))*8 + (k&7).
// Per K-tile: 4 phases (quadrant = m-half x n-pair), 16 MFMA each.
// Staging one K-tile ahead: A via global_load_lds (pre-swizzled source),
// B f32 reg-loaded 2 phases before cvt+ds_write.
//
// SYNC CONTRACT (r8, re-verified):
//  * vmcnt is PER-WAVE while staging is COOPERATIVE -> every wait for
//    cooperative data sits IMMEDIATELY BEFORE a barrier; reads happen
//    after that barrier. Per-wave VM FIFO per iter (2 GLDA | 4 B | 4 B |
//    2 GLDA): VMW(6) before q1's ending BAR drains A rows 64/192 of tile
//    kt (read at q2); VMW(10) before q3's ending BAR drains A rows 0/128
//    of tile kt+1 (read at q0').
//  * ds_write visibility: WRB; BAR; own-wave LGKM0 (drains own WRB and own
//    ds_reads) before the NEXT BAR releases readers.
//  * VMW(0) after the loop: no gld16 may outlive the block.
//  * All barriers fenced (zero-cost) so plain loads / GLDA cannot drift
//    across phases; per-phase VM ops are homogeneous so the FIFO count
//    is exact regardless of within-phase scheduling.

#define GDECL \
  __shared__ u16 AsH[2 * 256 * 64]; \
  __shared__ u16 BsH[2 * 256 * 64]; \
  const int t = threadIdx.x; \
  const int l = t & 63; \
  const int w = t >> 6; \
  const int wm = w >> 2; \
  const int wn = w & 3; \
  const int lrow = l & 15; \
  const int kb = l >> 4; \
  const int rsw0_ = ((kb) ^ (l & 7)) * 8; \
  const int rsw1_ = ((4 + kb) ^ (l & 7)) * 8; \
  const int arow_ = w * 8 + (l >> 3); \
  const int asw_ = ((l & 7) ^ (l >> 3)) * 8; \
  const int brow_ = (t >> 7) * 64 + ((t >> 2) & 31); \
  const int bkq_ = t & 3; \
  const int bsa_ = ((bkq_ * 2) ^ (brow_ & 7)) * 8; \
  const int bsb_ = ((bkq_ * 2 + 1) ^ (brow_ & 7)) * 8;

#define GLDA(sl, rbase, ktS, abase, AST) do { \
  const u16* g_ = (abase) + (size_t)((rbase) + arow_) * (AST) + (size_t)(ktS) * 64 + asw_; \
  gld16(g_, (char*)AsH + (sl) * 32768 + (rbase) * 128 + t * 16); \
} while (0)

#define LOADB(dst, ktS, u, bbase, BST) do { \
  const float4* p_ = (const float4*)((bbase) + (size_t)(brow_ + (u) * 32) * (BST) + (size_t)(ktS) * 64 + bkq_ * 16); \
  dst[0] = p_[0]; dst[1] = p_[1]; dst[2] = p_[2]; dst[3] = p_[3]; \
} while (0)

#define WRB(sl, u, src) do { \
  uint4 w0_, w1_; \
  w0_.x = pkbf2(src[0].x, src[0].y); w0_.y = pkbf2(src[0].z, src[0].w); \
  w0_.z = pkbf2(src[1].x, src[1].y); w0_.w = pkbf2(src[1].z, src[1].w); \
  w1_.x = pkbf2(src[2].x, src[2].y); w1_.y = pkbf2(src[2].z, src[2].w); \
  w1_.z = pkbf2(src[3].x, src[3].y); w1_.w = pkbf2(src[3].z, src[3].w); \
  *(uint4*)&BsH[(sl) * 16384 + (brow_ + (u) * 32) * 64 + bsa_] = w0_; \
  *(uint4*)&BsH[(sl) * 16384 + (brow_ + (u) * 32) * 64 + bsb_] = w1_; \
} while (0)

#define RDA(mh, slotH) do { \
  _Pragma("unroll") for (int ml_ = 0; ml_ < 4; ++ml_) { \
    const int r_ = wm * 128 + ((mh) * 4 + ml_) * 16 + lrow; \
    af[ml_][0] = *(const bf16x8*)&AsH[(slotH) + r_ * 64 + rsw0_]; \
    af[ml_][1] = *(const bf16x8*)&AsH[(slotH) + r_ * 64 + rsw1_]; \
  } \
} while (0)

#define RDB(np, slotH) do { \
  _Pragma("unroll") for (int nl_ = 0; nl_ < 2; ++nl_) { \
    const int r_ = wn * 64 + ((np) * 2 + nl_) * 16 + lrow; \
    bf[nl_][0] = *(const bf16x8*)&BsH[(slotH) + r_ * 64 + rsw0_]; \
    bf[nl_][1] = *(const bf16x8*)&BsH[(slotH) + r_ * 64 + rsw1_]; \
  } \
} while (0)

#define MFMA16(mh, np) do { \
  _Pragma("unroll") for (int ml_ = 0; ml_ < 4; ++ml_) \
    _Pragma("unroll") for (int nl_ = 0; nl_ < 2; ++nl_) \
      _Pragma("unroll") for (int ks_ = 0; ks_ < 2; ++ks_) \
        acc[(mh) * 4 + ml_][(np) * 2 + nl_] = __builtin_amdgcn_mfma_f32_16x16x32_bf16( \
            af[ml_][ks_], bf[nl_][ks_], acc[(mh) * 4 + ml_][(np) * 2 + nl_], 0, 0, 0); \
} while (0)

#define FENCE() asm volatile("" ::: "memory")
#define BAR()  do { FENCE(); __builtin_amdgcn_s_barrier(); FENCE(); } while (0)
#define LGKM0() asm volatile("s_waitcnt lgkmcnt(0)" ::: "memory")
#define VMW(n) asm volatile("s_waitcnt vmcnt(" #n ")" ::: "memory")

#define GEMM_CORE(NKT, abase, AST, bbase, BST) \
  f32x4 acc[8][4]; \
  _Pragma("unroll") for (int m_ = 0; m_ < 8; ++m_) \
    _Pragma("unroll") for (int n_ = 0; n_ < 4; ++n_) \
      acc[m_][n_] = (f32x4){0.f, 0.f, 0.f, 0.f}; \
  bf16x8 af[4][2]; \
  float4 fq[4], fu1[4]; \
  /* prologue: stage K-tile 0 into slot 0, fully drained before BAR */ \
  GLDA(0, 0, 0, abase, AST); GLDA(0, 128, 0, abase, AST); \
  GLDA(0, 64, 0, abase, AST); GLDA(0, 192, 0, abase, AST); \
  LOADB(fq, 0, 0, bbase, BST); \
  LOADB(fu1, 0, 1, bbase, BST); \
  WRB(0, 0, fq); \
  VMW(0); \
  LGKM0(); \
  BAR(); \
  _Pragma("unroll 2") \
  for (int kt = 0; kt < (NKT); ++kt) { \
    const int slot = kt & 1, ss_ = slot ^ 1; \
    const int slotH = slot * 16384; \
    const int ktS = (kt + 1 < (NKT)) ? kt + 1 : 0; \
    { /* q0: mhalf0 x np0 */ \
      bf16x8 bf[2][2]; \
      RDA(0, slotH); RDB(0, slotH); \
      GLDA(ss_, 0, ktS, abase, AST); GLDA(ss_, 128, ktS, abase, AST); \
      WRB(slot, 1, fu1); /* B_u1(kt), loaded 2 phases ago */ \
      BAR(); LGKM0(); \
      __builtin_amdgcn_s_setprio(1); MFMA16(0, 0); __builtin_amdgcn_s_setprio(0); \
      BAR(); \
    } \
    { /* q1: mhalf0 x np1 */ \
      bf16x8 bf[2][2]; \
      RDB(1, slotH); \
      LOADB(fq, ktS, 0, bbase, BST); \
      BAR(); LGKM0(); \
      __builtin_amdgcn_s_setprio(1); MFMA16(0, 1); __builtin_amdgcn_s_setprio(0); \
      VMW(6);  /* A rows 64/192 of tile kt landed before next BAR */ \
      BAR(); \
    } \
    { /* q2: mhalf1 x np0 */ \
      bf16x8 bf[2][2]; \
      RDA(1, slotH); RDB(0, slotH); \
      LOADB(fu1, ktS, 1, bbase, BST); \
      BAR(); LGKM0(); \
      __builtin_amdgcn_s_setprio(1); MFMA16(1, 0); __builtin_amdgcn_s_setprio(0); \
      BAR(); \
    } \
    { /* q3: mhalf1 x np1 */ \
      bf16x8 bf[2][2]; \
      RDB(1, slotH); \
      GLDA(ss_, 64, ktS, abase, AST); GLDA(ss_, 192, ktS, abase, AST); \
      WRB(ss_, 0, fq); /* B_u0(kt+1) */ \
      BAR(); LGKM0(); \
      __builtin_amdgcn_s_setprio(1); MFMA16(1, 1); __builtin_amdgcn_s_setprio(0); \
      VMW(10); /* A rows 0/128 of tile kt+1 landed before next BAR */ \
      BAR(); \
    } \
  } \
  VMW(0); /* no gld16 may outlive this block (LDS reuse by next WG) */

// ---------------- G1: H = relu(Xd Wk^T)^2, bf16 ----------------
__global__ __launch_bounds__(512, 2) void g1(const u16* __restrict__ Xd,
                                             const float* __restrict__ Wk,
                                             u16* __restrict__ H) {
  GDECL
  const int wg = (blockIdx.x & 7) * 112 + (blockIdx.x >> 3);  // 896 blocks
  const int e = wg / 14, rem = wg % 14;
  const int m0 = (rem & 1) * 256;
  const int n0 = (rem >> 1) * 256;
  const u16*  abase = Xd + ((size_t)e * CAP + m0) * ND;
  const float* bbase = Wk + ((size_t)e * NF + n0) * ND;
  GEMM_CORE(8, abase, ND, bbase, ND)

  #pragma unroll
  for (int m = 0; m < 8; ++m) {
    #pragma unroll
    for (int i = 0; i < 4; ++i) {
      int r = m0 + wm * 128 + m * 16 + (l >> 4) * 4 + i;
      size_t base = ((size_t)e * CAP + r) * NF + n0 + wn * 64 + lrow;
      #pragma unroll
      for (int n = 0; n < 4; ++n) {
        float v = acc[m][n][i];
        v = v > 0.f ? v * v : 0.f;
        H[base + n * 16] = f2bf(v);
      }
    }
  }
}

// ---------------- G2a: R = sigmoid(Xd Wr^T), fp16 ----------------
__global__ __launch_bounds__(512, 2) void g2a(const u16* __restrict__ Xd,
                                              const float* __restrict__ Wr,
                                              __half* __restrict__ R) {
  GDECL
  const int wg = (blockIdx.x & 7) * 32 + (blockIdx.x >> 3);  // 256 blocks
  const int e = wg >> 2, rem = wg & 3;
  const int m0 = (rem & 1) * 256;
  const int n0 = (rem >> 1) * 256;
  const u16*  abase = Xd + ((size_t)e * CAP + m0) * ND;
  const float* bbase = Wr + ((size_t)e * ND + n0) * ND;
  GEMM_CORE(8, abase, ND, bbase, ND)

  #pragma unroll
  for (int m = 0; m < 8; ++m) {
    #pragma unroll
    for (int i = 0; i < 4; ++i) {
      int r = m0 + wm * 128 + m * 16 + (l >> 4) * 4 + i;
      size_t base = ((size_t)e * CAP + r) * ND + n0 + wn * 64 + lrow;
      #pragma unroll
      for (int n = 0; n < 4; ++n) {
        float s = 1.f / (1.f + __expf(-acc[m][n][i]));
        R[base + n * 16] = __float2half(s);
      }
    }
  }
}

// ---------------- G2b: out = R * (H Wv^T), scatter ----------------
__global__ __launch_bounds__(512, 2) void g2b(const u16* __restrict__ H,
                                              const float* __restrict__ Wv,
                                              const __half* __restrict__ R,
                                              const int* __restrict__ slot_src,
                                              float* __restrict__ out) {
  GDECL
  const int wg = (blockIdx.x & 7) * 32 + (blockIdx.x >> 3);  // 256 blocks
  const int e = wg >> 2, rem = wg & 3;
  const int m0 = (rem & 1) * 256;
  const int n0 = (rem >> 1) * 256;
  const u16*  abase = H  + ((size_t)e * CAP + m0) * NF;
  const float* bbase = Wv + ((size_t)e * ND + n0) * NF;
  GEMM_CORE(28, abase, NF, bbase, NF)

  #pragma unroll
  for (int m = 0; m < 8; ++m) {
    #pragma unroll
    for (int i = 0; i < 4; ++i) {
      int rl = m0 + wm * 128 + m * 16 + (l >> 4) * 4 + i;
      int s = slot_src[e * CAP + rl];
      if (s >= 0) {
        const __half* rp = R + ((size_t)e * CAP + rl) * ND + n0 + wn * 64 + lrow;
        float* op = out + (size_t)s * ND + n0 + wn * 64 + lrow;
        #pragma unroll
        for (int n = 0; n < 4; ++n) {
          op[n * 16] = __half2float(rp[n * 16]) * acc[m][n][i];
        }
      }
    }
  }
}

extern "C" void kernel_launch(void* const* d_in, const int* in_sizes, int n_in,
                              void* d_out, int out_size, void* d_ws, size_t ws_size,
                              hipStream_t stream) {
  const float* x   = (const float*)d_in[0];
  const int*   tok = (const int*)d_in[1];
  const float* Wk  = (const float*)d_in[2];
  const float* Wr  = (const float*)d_in[3];
  const float* Wv  = (const float*)d_in[4];
  float* out = (float*)d_out;

  char* ws = (char*)d_ws;
  int*    slot_src   = (int*)ws;
  int*    rank_local = (int*)(ws + 131072);
  int*    hist       = (int*)(ws + 262144);
  u16*    Xd         = (u16*)(ws + (1 << 20));
  __half* R          = (__half*)(ws + 34603008);
  u16*    Hbuf       = (u16*)(ws + 68157440);

  (void)hipMemsetAsync(d_out, 0, (size_t)out_size * sizeof(float), stream);
  (void)hipMemsetAsync(slot_src, 0xFF, NE * CAP * sizeof(int), stream);
  route1<<<64, 512, 0, stream>>>(tok, rank_local, hist);
  route2<<<64, 512, 0, stream>>>(tok, rank_local, hist, slot_src);
  dispatchx<<<NS / 4, 256, 0, stream>>>(x, slot_src, Xd);
  g1 <<<896, 512, 0, stream>>>(Xd, Wk, Hbuf);
  g2a<<<256, 512, 0, stream>>>(Xd, Wr, R);
  g2b<<<256, 512, 0, stream>>>(Hbuf, Wv, R, slot_src, out);
}